// Round 9
// baseline (6149.588 us; speedup 1.0000x reference)
//
#include <hip/hip_runtime.h>
#include <hip/hip_bf16.h>

#define S_LEN 512
#define BATCH 64
#define EMB_D 256
#define HID   512
#define NTAG  5

typedef unsigned short u16;
typedef unsigned long long u64;
typedef __attribute__((ext_vector_type(8)))  short bf16x8;
typedef __attribute__((ext_vector_type(16))) float f32x16;

__device__ __forceinline__ float bf2f(u16 u) {
  union { unsigned int i; float f; } v; v.i = ((unsigned int)u) << 16; return v.f;
}
__device__ __forceinline__ u16 f2bf(float f) {
  __hip_bfloat16 h = __float2bfloat16(f);
  union { __hip_bfloat16 h; u16 u; } v; v.h = h; return v.u;
}
__device__ __forceinline__ float sigm(float x) { return 1.0f / (1.0f + __expf(-x)); }
__device__ __forceinline__ float ftanh(float x) {
  float ax = fabsf(x);
  float e  = __expf(-2.0f * ax);
  float t  = (1.0f - e) / (1.0f + e);
  return copysignf(t, x);
}

// pinned 16B global load, normal caching (read-only weights, loaded once;
// asm prevents rematerialization under register pressure)
__device__ __forceinline__ bf16x8 ldg_pin16(const u16* p) {
  float4 r;
  asm volatile("global_load_dwordx4 %0, %1, off" : "=v"(r) : "v"(p));
  return __builtin_bit_cast(bf16x8, r);
}

// ---------------- weight prep: Wcat bf16 [2][2048][768] = [Wih | Whh], bias fp32 [2][2048]
__global__ void k_prep_w(const float* __restrict__ wihf, const float* __restrict__ whhf,
                         const float* __restrict__ bihf, const float* __restrict__ bhhf,
                         const float* __restrict__ wihb, const float* __restrict__ whhb,
                         const float* __restrict__ bihb, const float* __restrict__ bhhb,
                         u16* __restrict__ Wcat, float* __restrict__ bias)
{
  const int gid = blockIdx.x * blockDim.x + threadIdx.x;
  const int k4  = gid % 192;
  const int rem = gid / 192;
  const int row = rem & 2047;
  const int d   = rem >> 11;
  const float* wih = d ? wihb : wihf;
  const float* whh = d ? whhb : whhf;
  const int k = k4 * 4;
  float4 v;
  if (k < EMB_D) v = *(const float4*)(wih + (size_t)row * EMB_D + k);
  else           v = *(const float4*)(whh + (size_t)row * HID + (k - EMB_D));
  union { u16 u[4]; uint2 q; } pk;
  pk.u[0] = f2bf(v.x); pk.u[1] = f2bf(v.y); pk.u[2] = f2bf(v.z); pk.u[3] = f2bf(v.w);
  *(uint2*)(Wcat + ((size_t)(d * 2048 + row)) * 768 + k) = pk.q;
  if (gid < 4096) {
    const int dd = gid >> 11, r = gid & 2047;
    bias[gid] = dd ? (bihb[r] + bhhb[r]) : (bihf[r] + bhhf[r]);
  }
}

// ---------------- embedding gather -> xz bf16 [S][B][EMB]
__global__ void k_embed(const int* __restrict__ text, const float* __restrict__ emb,
                        u16* __restrict__ xz)
{
  const int gid = blockIdx.x * blockDim.x + threadIdx.x;
  const int e4 = gid & 63;
  const int sb = gid >> 6;
  const int b  = sb & 63;
  const int s  = sb >> 6;
  const int row = text[b * S_LEN + s];
  float4 v = *(const float4*)(emb + (size_t)row * EMB_D + e4 * 4);
  union { u16 u[4]; uint2 q; } pk;
  pk.u[0] = f2bf(v.x); pk.u[1] = f2bf(v.y); pk.u[2] = f2bf(v.z); pk.u[3] = f2bf(v.w);
  *(uint2*)(xz + ((size_t)(s * BATCH + b)) * EMB_D + e4 * 4) = pk.q;
}

// ---------------- persistent MFMA BiLSTM, no LDS, no cache-maintenance ops ----
// 64 blocks x 4 waves. Block: d = bid>>5, hid base k0 = (bid&31)*16.
// Wave: rt = w>>1 (8 hidden units), nt = w&1 (batch half). A rows m=0..31 ->
// gate q=m>>3, hid=hbase+(m&7) => acc reg r: gate=r>>2, hid_local=(r&3)+4*lhi,
// batch col=lane&31 => LSTM cell fully per-lane.
// h-exchange is device-coherent BY CONSTRUCTION: relaxed agent-scope atomic
// stores/loads (sc0 sc1, through MALL). No wbl2/inv anywhere -> L2 stays hot.
//   writer: atomic stores -> __syncthreads (vmcnt0 drain: sc1 stores at MALL)
//           -> tid0 relaxed atomicAdd flag
//   reader: tid0 relaxed poll -> wg-acquire fence -> __syncthreads -> atomic loads
__launch_bounds__(256, 1)
__global__ void k_lstm(const u16* __restrict__ Wcat, const float* __restrict__ bias,
                       const u16* __restrict__ xz, u16* __restrict__ hbuf,
                       int* __restrict__ cnt)
{
  const int bid  = blockIdx.x;
  const int d    = bid >> 5;
  const int k0   = (bid & 31) * 16;
  const int tid  = threadIdx.x;
  const int w    = tid >> 6;
  const int lane = tid & 63;
  const int rt   = w >> 1, nt = w & 1;
  const int ln31 = lane & 31, lhi = lane >> 5;
  const int hbase = k0 + rt * 8;
  const int bcol  = nt * 32 + ln31;

  // ---- A fragments, pinned in registers (read-only data, loaded once) ----
  bf16x8 af[48];
  {
    const int m    = ln31;
    const int grow = (m >> 3) * HID + hbase + (m & 7);
    const u16* wr  = Wcat + ((size_t)(d * 2048 + grow)) * 768 + lhi * 8;
    #pragma unroll
    for (int ks = 0; ks < 48; ++ks) af[ks] = ldg_pin16(wr + ks * 16);
  }
  asm volatile("s_waitcnt vmcnt(0)" ::: "memory");
  __builtin_amdgcn_sched_barrier(0);

  // ---- per-lane bias seed (gate q, hid_local i+4*lhi) ----
  float bsv[16];
  #pragma unroll
  for (int q = 0; q < 4; ++q)
    #pragma unroll
    for (int i = 0; i < 4; ++i)
      bsv[q * 4 + i] = bias[d * 2048 + q * HID + hbase + 4 * lhi + i];
  float cst[4] = {0.f, 0.f, 0.f, 0.f};

  for (int it = 0; it < S_LEN; ++it) {
    const int t = d ? (S_LEN - 1 - it) : it;

    // two accumulators halve the dependent-MFMA chain; combined at the cell
    f32x16 acc0, acc1;
    #pragma unroll
    for (int r = 0; r < 16; ++r) { acc0[r] = bsv[r]; acc1[r] = 0.f; }

    // ---- x-part (independent of h; L2-hot; overlaps the poll below) ----
    {
      const u16* xb = xz + ((size_t)t * BATCH + bcol) * EMB_D + lhi * 8;
      #pragma unroll
      for (int c = 0; c < 16; ++c) {
        bf16x8 xf = *(const bf16x8*)(xb + c * 16);
        if (c & 1) acc1 = __builtin_amdgcn_mfma_f32_32x32x16_bf16(af[c], xf, acc1, 0, 0, 0);
        else       acc0 = __builtin_amdgcn_mfma_f32_32x32x16_bf16(af[c], xf, acc0, 0, 0, 0);
      }
    }

    // ---- wait for h_{prev}: tid0 polls, then device-coherent loads ----
    if (it > 0) {
      if (tid == 0) {
        const int* flg = cnt + (size_t)(d * S_LEN + it - 1) * 16;
        while (__hip_atomic_load(flg, __ATOMIC_RELAXED, __HIP_MEMORY_SCOPE_AGENT) < 32)
          __builtin_amdgcn_s_sleep(1);
      }
      __builtin_amdgcn_fence(__ATOMIC_ACQUIRE, "workgroup");  // order poll->loads, no L2 ops
      __syncthreads();   // no wave's h-loads may begin before the poll succeeds

      const int tprev = d ? (t + 1) : (t - 1);
      // fragment c covers k = c*16 + lhi*8 + [0,8)  (u64 idx = c*4 + lhi*2)
      const u64* hb = (const u64*)(hbuf + (((size_t)d * S_LEN + tprev) * BATCH + bcol) * HID);
      #pragma unroll
      for (int c = 0; c < 32; ++c) {
        union { u64 q[2]; bf16x8 v; } hf;
        hf.q[0] = __hip_atomic_load(hb + c * 4 + lhi * 2,
                                    __ATOMIC_RELAXED, __HIP_MEMORY_SCOPE_AGENT);
        hf.q[1] = __hip_atomic_load(hb + c * 4 + lhi * 2 + 1,
                                    __ATOMIC_RELAXED, __HIP_MEMORY_SCOPE_AGENT);
        if (c & 1) acc1 = __builtin_amdgcn_mfma_f32_32x32x16_bf16(af[16 + c], hf.v, acc1, 0, 0, 0);
        else       acc0 = __builtin_amdgcn_mfma_f32_32x32x16_bf16(af[16 + c], hf.v, acc0, 0, 0, 0);
      }
    }

    // ---- LSTM cell, fully per-lane ----
    u16 hu[4];
    #pragma unroll
    for (int i = 0; i < 4; ++i) {
      const float gi = acc0[i]      + acc1[i];
      const float gf = acc0[4 + i]  + acc1[4 + i];
      const float gg = acc0[8 + i]  + acc1[8 + i];
      const float go = acc0[12 + i] + acc1[12 + i];
      const float ig = sigm(gi), fg = sigm(gf), g2 = ftanh(gg), og = sigm(go);
      cst[i] = fg * cst[i] + ig * g2;
      hu[i] = f2bf(og * ftanh(cst[i]));
    }
    const u64 pk = (u64)hu[0] | ((u64)hu[1] << 16) | ((u64)hu[2] << 32) | ((u64)hu[3] << 48);
    u64* hw = (u64*)(hbuf + (((size_t)d * S_LEN + t) * BATCH + bcol) * HID + hbase + 4 * lhi);
    __hip_atomic_store(hw, pk, __ATOMIC_RELAXED, __HIP_MEMORY_SCOPE_AGENT);  // sc0sc1 -> MALL

    __syncthreads();   // emits s_waitcnt vmcnt(0): all waves' sc1 stores acked at MALL
    if (tid == 0) {
      asm volatile("s_waitcnt vmcnt(0)" ::: "memory");   // belt & suspenders (already drained)
      __hip_atomic_fetch_add(cnt + (size_t)(d * S_LEN + it) * 16, 1,
                             __ATOMIC_RELAXED, __HIP_MEMORY_SCOPE_AGENT);
    }
  }
}

// ---------------- heads: em[s][b][j] = [hf;hb] . w[j] + bias[j] ----------------
__global__ void k_heads(const u16* __restrict__ hbuf,
                        const float* __restrict__ sbj_w, const float* __restrict__ sbj_b,
                        const float* __restrict__ obj_w, const float* __restrict__ obj_b,
                        float* __restrict__ em_s, float* __restrict__ em_o)
{
  const int wid  = blockIdx.x * 4 + (threadIdx.x >> 6);
  const int lane = threadIdx.x & 63;
  if (wid >= S_LEN * BATCH) return;
  const int s = wid >> 6, b = wid & 63;
  const int dsel = lane >> 5;
  const int off  = (lane * 16) & 511;
  const u16* src = hbuf + (((size_t)dsel * S_LEN + s) * BATCH + b) * HID + off;
  uint4 p0 = *(const uint4*)(src);
  uint4 p1 = *(const uint4*)(src + 8);
  unsigned int pw[8] = { p0.x, p0.y, p0.z, p0.w, p1.x, p1.y, p1.z, p1.w };
  float z[16];
  #pragma unroll
  for (int i = 0; i < 8; ++i) {
    z[2 * i]     = bf2f((u16)(pw[i] & 0xffffu));
    z[2 * i + 1] = bf2f((u16)(pw[i] >> 16));
  }
  #pragma unroll
  for (int r = 0; r < 10; ++r) {
    const float* wr = (r < 5) ? (sbj_w + r * (2 * HID)) : (obj_w + (r - 5) * (2 * HID));
    float p = 0.f;
    #pragma unroll
    for (int m4 = 0; m4 < 4; ++m4) {
      float4 w4 = *(const float4*)(wr + lane * 16 + m4 * 4);
      p += w4.x * z[m4*4] + w4.y * z[m4*4+1] + w4.z * z[m4*4+2] + w4.w * z[m4*4+3];
    }
    #pragma unroll
    for (int offs = 32; offs; offs >>= 1) p += __shfl_down(p, offs);
    if (lane == 0) {
      if (r < 5) em_s[(size_t)wid * NTAG + r]       = p + sbj_b[r];
      else       em_o[(size_t)wid * NTAG + (r - 5)] = p + obj_b[r - 5];
    }
  }
}

// ---------------- CRF NLL per (crf, batch): one wave each ----------------
__global__ void k_crf(const float* __restrict__ em_s, const float* __restrict__ em_o,
                      const int* __restrict__ sbjs, const int* __restrict__ objs,
                      const int* __restrict__ text,
                      const float* __restrict__ s_st, const float* __restrict__ s_en,
                      const float* __restrict__ s_tr,
                      const float* __restrict__ o_st, const float* __restrict__ o_en,
                      const float* __restrict__ o_tr,
                      float* __restrict__ perb, float* __restrict__ cntb)
{
  const int c = blockIdx.x & 1;
  const int b = blockIdx.x >> 1;
  const int j = threadIdx.x;

  const float* em    = c ? em_o : em_s;
  const int*   tags  = c ? objs : sbjs;
  const float* start = c ? o_st : s_st;
  const float* endv  = c ? o_en : s_en;
  const float* trans = c ? o_tr : s_tr;

  float num = 0.f, cnt = 0.f;
  for (int s = j; s < S_LEN; s += 64) {
    const int m = (text[b * S_LEN + s] != 0) ? 1 : 0;
    cnt += (float)m;
    const int tg = tags[b * S_LEN + s];
    if (s == 0) {
      num += start[tg] + em[(size_t)b * NTAG + tg];
    } else if (m) {
      const int tp = tags[b * S_LEN + s - 1];
      num += trans[tp * NTAG + tg] + em[((size_t)s * BATCH + b) * NTAG + tg];
    }
  }
  #pragma unroll
  for (int off = 32; off; off >>= 1) { num += __shfl_down(num, off); cnt += __shfl_down(cnt, off); }
  num = __shfl(num, 0); cnt = __shfl(cnt, 0);
  const int seq_end = (int)cnt - 1;
  if (j == 0) num += endv[tags[b * S_LEN + seq_end]];

  float tr0 = 0, tr1 = 0, tr2 = 0, tr3 = 0, tr4 = 0, st = 0, en = 0;
  if (j < NTAG) {
    tr0 = trans[0 * NTAG + j]; tr1 = trans[1 * NTAG + j]; tr2 = trans[2 * NTAG + j];
    tr3 = trans[3 * NTAG + j]; tr4 = trans[4 * NTAG + j];
    st = start[j]; en = endv[j];
  }
  float alpha = (j < NTAG) ? (st + em[(size_t)b * NTAG + j]) : -1e30f;
  for (int s = 1; s < S_LEN; ++s) {
    const float a0 = __shfl(alpha, 0), a1 = __shfl(alpha, 1), a2 = __shfl(alpha, 2),
                a3 = __shfl(alpha, 3), a4 = __shfl(alpha, 4);
    const int m = (text[b * S_LEN + s] != 0);
    if (j < NTAG) {
      const float v0 = a0 + tr0, v1 = a1 + tr1, v2 = a2 + tr2, v3 = a3 + tr3, v4 = a4 + tr4;
      float mx = fmaxf(fmaxf(fmaxf(v0, v1), fmaxf(v2, v3)), v4);
      float sm = expf(v0 - mx) + expf(v1 - mx) + expf(v2 - mx) + expf(v3 - mx) + expf(v4 - mx);
      float nxt = mx + logf(sm) + em[((size_t)s * BATCH + b) * NTAG + j];
      if (m) alpha = nxt;
    }
  }
  float v  = (j < NTAG) ? (alpha + en) : -1e30f;
  float mx = v;
  #pragma unroll
  for (int off = 1; off < 8; off <<= 1) mx = fmaxf(mx, __shfl_xor(mx, off));
  float ex = (j < NTAG) ? expf(v - mx) : 0.f;
  #pragma unroll
  for (int off = 1; off < 8; off <<= 1) ex += __shfl_xor(ex, off);
  if (j == 0) {
    perb[c * BATCH + b] = num - (mx + logf(ex));
    cntb[c * BATCH + b] = cnt;
  }
}

__global__ void k_final(const float* __restrict__ perb, const float* __restrict__ cntb,
                        float* __restrict__ out)
{
  if (threadIdx.x == 0 && blockIdx.x == 0) {
    float s0 = 0, c0 = 0, s1 = 0, c1 = 0;
    for (int b = 0; b < BATCH; ++b) {
      s0 += perb[b];         c0 += cntb[b];
      s1 += perb[BATCH + b]; c1 += cntb[BATCH + b];
    }
    const float ls = -s0 / c0, lo = -s1 / c1;
    out[0] = 2.f * (ls + lo);
    out[1] = ls;
    out[2] = lo;
  }
}

extern "C" void kernel_launch(void* const* d_in, const int* in_sizes, int n_in,
                              void* d_out, int out_size, void* d_ws, size_t ws_size,
                              hipStream_t stream)
{
  const int*   text  = (const int*)d_in[0];
  const int*   sbjs  = (const int*)d_in[1];
  const int*   objs  = (const int*)d_in[2];
  const float* emb   = (const float*)d_in[3];
  const float* wih_f = (const float*)d_in[4];
  const float* whh_f = (const float*)d_in[5];
  const float* bih_f = (const float*)d_in[6];
  const float* bhh_f = (const float*)d_in[7];
  const float* wih_b = (const float*)d_in[8];
  const float* whh_b = (const float*)d_in[9];
  const float* bih_b = (const float*)d_in[10];
  const float* bhh_b = (const float*)d_in[11];
  const float* sbj_w = (const float*)d_in[12];
  const float* sbj_b = (const float*)d_in[13];
  const float* obj_w = (const float*)d_in[14];
  const float* obj_b = (const float*)d_in[15];
  const float* s_st  = (const float*)d_in[16];
  const float* s_en  = (const float*)d_in[17];
  const float* s_tr  = (const float*)d_in[18];
  const float* o_st  = (const float*)d_in[19];
  const float* o_en  = (const float*)d_in[20];
  const float* o_tr  = (const float*)d_in[21];

  char* w = (char*)d_ws;
  u16*   Wcat = (u16*)(w + 0);            //  6,291,456 B
  float* bias = (float*)(w + 6291456);    //     16,384 B
  u16*   xz   = (u16*)(w + 6307840);      // 16,777,216 B
  u16*   hbuf = (u16*)(w + 23085056);     // 67,108,864 B
  float* em_s = (float*)(w + 90193920);   //    655,360 B
  float* em_o = (float*)(w + 90849280);   //    655,360 B
  float* perb = (float*)(w + 91504640);   //        512 B
  float* cntb = (float*)(w + 91505152);   //        512 B
  int*   cnt  = (int*)(w + 91505664);     //     65,536 B

  hipMemsetAsync(cnt, 0, 2 * S_LEN * 16 * sizeof(int), stream);

  k_prep_w<<<3072, 256, 0, stream>>>(wih_f, whh_f, bih_f, bhh_f,
                                     wih_b, whh_b, bih_b, bhh_b, Wcat, bias);
  k_embed<<<8192, 256, 0, stream>>>(text, emb, xz);

  void* args[] = { (void*)&Wcat, (void*)&bias, (void*)&xz, (void*)&hbuf, (void*)&cnt };
  hipLaunchCooperativeKernel((const void*)k_lstm, dim3(64), dim3(256), args, 0, stream);

  k_heads<<<8192, 256, 0, stream>>>(hbuf, sbj_w, sbj_b, obj_w, obj_b, em_s, em_o);
  k_crf<<<128, 64, 0, stream>>>(em_s, em_o, sbjs, objs, text,
                                s_st, s_en, s_tr, o_st, o_en, o_tr, perb, cntb);
  k_final<<<1, 1, 0, stream>>>(perb, cntb, (float*)d_out);
}

// Round 10
// 6022.398 us; speedup vs baseline: 1.0211x; 1.0211x over previous
//
#include <hip/hip_runtime.h>
#include <hip/hip_bf16.h>

#define S_LEN 512
#define BATCH 64
#define EMB_D 256
#define HID   512
#define NTAG  5

typedef unsigned short u16;
typedef unsigned long long u64;
typedef __attribute__((ext_vector_type(8)))  short bf16x8;
typedef __attribute__((ext_vector_type(16))) float f32x16;

__device__ __forceinline__ float bf2f(u16 u) {
  union { unsigned int i; float f; } v; v.i = ((unsigned int)u) << 16; return v.f;
}
__device__ __forceinline__ u16 f2bf(float f) {
  __hip_bfloat16 h = __float2bfloat16(f);
  union { __hip_bfloat16 h; u16 u; } v; v.h = h; return v.u;
}
__device__ __forceinline__ float sigm(float x) { return 1.0f / (1.0f + __expf(-x)); }
__device__ __forceinline__ float ftanh(float x) {
  float ax = fabsf(x);
  float e  = __expf(-2.0f * ax);
  float t  = (1.0f - e) / (1.0f + e);
  return copysignf(t, x);
}

// pinned 16B global load, normal caching (read-only weights, loaded once;
// asm prevents rematerialization under register pressure)
__device__ __forceinline__ bf16x8 ldg_pin16(const u16* p) {
  float4 r;
  asm volatile("global_load_dwordx4 %0, %1, off" : "=v"(r) : "v"(p));
  return __builtin_bit_cast(bf16x8, r);
}

// ---------------- weight prep: Wcat bf16 [2][2048][768] = [Wih | Whh], bias fp32 [2][2048]
__global__ void k_prep_w(const float* __restrict__ wihf, const float* __restrict__ whhf,
                         const float* __restrict__ bihf, const float* __restrict__ bhhf,
                         const float* __restrict__ wihb, const float* __restrict__ whhb,
                         const float* __restrict__ bihb, const float* __restrict__ bhhb,
                         u16* __restrict__ Wcat, float* __restrict__ bias)
{
  const int gid = blockIdx.x * blockDim.x + threadIdx.x;
  const int k4  = gid % 192;
  const int rem = gid / 192;
  const int row = rem & 2047;
  const int d   = rem >> 11;
  const float* wih = d ? wihb : wihf;
  const float* whh = d ? whhb : whhf;
  const int k = k4 * 4;
  float4 v;
  if (k < EMB_D) v = *(const float4*)(wih + (size_t)row * EMB_D + k);
  else           v = *(const float4*)(whh + (size_t)row * HID + (k - EMB_D));
  union { u16 u[4]; uint2 q; } pk;
  pk.u[0] = f2bf(v.x); pk.u[1] = f2bf(v.y); pk.u[2] = f2bf(v.z); pk.u[3] = f2bf(v.w);
  *(uint2*)(Wcat + ((size_t)(d * 2048 + row)) * 768 + k) = pk.q;
  if (gid < 4096) {
    const int dd = gid >> 11, r = gid & 2047;
    bias[gid] = dd ? (bihb[r] + bhhb[r]) : (bihf[r] + bhhf[r]);
  }
}

// ---------------- embedding gather -> xz bf16 [S][B][EMB]
__global__ void k_embed(const int* __restrict__ text, const float* __restrict__ emb,
                        u16* __restrict__ xz)
{
  const int gid = blockIdx.x * blockDim.x + threadIdx.x;
  const int e4 = gid & 63;
  const int sb = gid >> 6;
  const int b  = sb & 63;
  const int s  = sb >> 6;
  const int row = text[b * S_LEN + s];
  float4 v = *(const float4*)(emb + (size_t)row * EMB_D + e4 * 4);
  union { u16 u[4]; uint2 q; } pk;
  pk.u[0] = f2bf(v.x); pk.u[1] = f2bf(v.y); pk.u[2] = f2bf(v.z); pk.u[3] = f2bf(v.w);
  *(uint2*)(xz + ((size_t)(s * BATCH + b)) * EMB_D + e4 * 4) = pk.q;
}

// ---------------- persistent MFMA BiLSTM, no LDS, no cache ops, no atomic RMW ----
// 64 blocks x 4 waves. Block: d = bid>>5, wb = bid&31, hid base k0 = wb*16.
// Wave: rt = w>>1 (8 hidden units), nt = w&1 (batch half). A rows m=0..31 ->
// gate q=m>>3, hid=hbase+(m&7) => acc reg r: gate=r>>2, hid_local=(r&3)+4*lhi,
// batch col=lane&31 => LSTM cell fully per-lane.
// Arrival: per-writer flags (flags[d][wb] = it+1, relaxed agent atomic STORE —
// no RMW, no serialization). Readers: each wave's lanes 0..31 poll the 32 flags
// (one coalesced line fetch/iter), __all(v >= it), acquire fence, then loads.
__launch_bounds__(256, 1)
__global__ void k_lstm(const u16* __restrict__ Wcat, const float* __restrict__ bias,
                       const u16* __restrict__ xz, u16* __restrict__ hbuf,
                       int* __restrict__ flags)
{
  const int bid  = blockIdx.x;
  const int d    = bid >> 5;
  const int wb   = bid & 31;
  const int k0   = wb * 16;
  const int tid  = threadIdx.x;
  const int w    = tid >> 6;
  const int lane = tid & 63;
  const int rt   = w >> 1, nt = w & 1;
  const int ln31 = lane & 31, lhi = lane >> 5;
  const int hbase = k0 + rt * 8;
  const int bcol  = nt * 32 + ln31;

  // ---- A fragments, pinned in registers (read-only data, loaded once) ----
  bf16x8 af[48];
  {
    const int m    = ln31;
    const int grow = (m >> 3) * HID + hbase + (m & 7);
    const u16* wr  = Wcat + ((size_t)(d * 2048 + grow)) * 768 + lhi * 8;
    #pragma unroll
    for (int ks = 0; ks < 48; ++ks) af[ks] = ldg_pin16(wr + ks * 16);
  }
  asm volatile("s_waitcnt vmcnt(0)" ::: "memory");
  __builtin_amdgcn_sched_barrier(0);

  // ---- per-lane bias seed (gate q, hid_local i+4*lhi) ----
  float bsv[16];
  #pragma unroll
  for (int q = 0; q < 4; ++q)
    #pragma unroll
    for (int i = 0; i < 4; ++i)
      bsv[q * 4 + i] = bias[d * 2048 + q * HID + hbase + 4 * lhi + i];
  float cst[4] = {0.f, 0.f, 0.f, 0.f};

  const int* myflags = flags + d * 32 + ln31;   // each lane polls one writer's flag

  for (int it = 0; it < S_LEN; ++it) {
    const int t = d ? (S_LEN - 1 - it) : it;

    // two accumulators halve the dependent-MFMA chain; combined at the cell
    f32x16 acc0, acc1;
    #pragma unroll
    for (int r = 0; r < 16; ++r) { acc0[r] = bsv[r]; acc1[r] = 0.f; }

    // ---- x-part (independent of h; L2-hot; overlaps the poll below) ----
    {
      const u16* xb = xz + ((size_t)t * BATCH + bcol) * EMB_D + lhi * 8;
      #pragma unroll
      for (int c = 0; c < 16; ++c) {
        bf16x8 xf = *(const bf16x8*)(xb + c * 16);
        if (c & 1) acc1 = __builtin_amdgcn_mfma_f32_32x32x16_bf16(af[c], xf, acc1, 0, 0, 0);
        else       acc0 = __builtin_amdgcn_mfma_f32_32x32x16_bf16(af[c], xf, acc0, 0, 0, 0);
      }
    }

    // ---- wait for h_{prev}: per-wave 32-lane flag poll (no RMW, no barrier) ----
    if (it > 0) {
      for (;;) {
        const int v = __hip_atomic_load(myflags, __ATOMIC_RELAXED,
                                        __HIP_MEMORY_SCOPE_AGENT);
        if (__all(v >= it)) break;
        __builtin_amdgcn_s_sleep(1);
      }
      __builtin_amdgcn_fence(__ATOMIC_ACQUIRE, "workgroup");  // order poll -> loads

      const int tprev = d ? (t + 1) : (t - 1);
      // fragment c covers k = c*16 + lhi*8 + [0,8)  (u64 idx = c*4 + lhi*2)
      const u64* hb = (const u64*)(hbuf + (((size_t)d * S_LEN + tprev) * BATCH + bcol) * HID);
      #pragma unroll
      for (int c = 0; c < 32; ++c) {
        union { u64 q[2]; bf16x8 v; } hf;
        hf.q[0] = __hip_atomic_load(hb + c * 4 + lhi * 2,
                                    __ATOMIC_RELAXED, __HIP_MEMORY_SCOPE_AGENT);
        hf.q[1] = __hip_atomic_load(hb + c * 4 + lhi * 2 + 1,
                                    __ATOMIC_RELAXED, __HIP_MEMORY_SCOPE_AGENT);
        if (c & 1) acc1 = __builtin_amdgcn_mfma_f32_32x32x16_bf16(af[16 + c], hf.v, acc1, 0, 0, 0);
        else       acc0 = __builtin_amdgcn_mfma_f32_32x32x16_bf16(af[16 + c], hf.v, acc0, 0, 0, 0);
      }
    }

    // ---- LSTM cell, fully per-lane ----
    u16 hu[4];
    #pragma unroll
    for (int i = 0; i < 4; ++i) {
      const float gi = acc0[i]      + acc1[i];
      const float gf = acc0[4 + i]  + acc1[4 + i];
      const float gg = acc0[8 + i]  + acc1[8 + i];
      const float go = acc0[12 + i] + acc1[12 + i];
      const float ig = sigm(gi), fg = sigm(gf), g2 = ftanh(gg), og = sigm(go);
      cst[i] = fg * cst[i] + ig * g2;
      hu[i] = f2bf(og * ftanh(cst[i]));
    }
    const u64 pk = (u64)hu[0] | ((u64)hu[1] << 16) | ((u64)hu[2] << 32) | ((u64)hu[3] << 48);
    u64* hw = (u64*)(hbuf + (((size_t)d * S_LEN + t) * BATCH + bcol) * HID + hbase + 4 * lhi);
    __hip_atomic_store(hw, pk, __ATOMIC_RELAXED, __HIP_MEMORY_SCOPE_AGENT);  // sc0sc1 -> MALL

    __syncthreads();   // vmcnt(0) drain: all 4 waves' h stores acked at MALL
    if (tid == 0)
      __hip_atomic_store(flags + d * 32 + wb, it + 1,
                         __ATOMIC_RELAXED, __HIP_MEMORY_SCOPE_AGENT);  // own word, no RMW
  }
}

// ---------------- heads: em[s][b][j] = [hf;hb] . w[j] + bias[j] ----------------
__global__ void k_heads(const u16* __restrict__ hbuf,
                        const float* __restrict__ sbj_w, const float* __restrict__ sbj_b,
                        const float* __restrict__ obj_w, const float* __restrict__ obj_b,
                        float* __restrict__ em_s, float* __restrict__ em_o)
{
  const int wid  = blockIdx.x * 4 + (threadIdx.x >> 6);
  const int lane = threadIdx.x & 63;
  if (wid >= S_LEN * BATCH) return;
  const int s = wid >> 6, b = wid & 63;
  const int dsel = lane >> 5;
  const int off  = (lane * 16) & 511;
  const u16* src = hbuf + (((size_t)dsel * S_LEN + s) * BATCH + b) * HID + off;
  uint4 p0 = *(const uint4*)(src);
  uint4 p1 = *(const uint4*)(src + 8);
  unsigned int pw[8] = { p0.x, p0.y, p0.z, p0.w, p1.x, p1.y, p1.z, p1.w };
  float z[16];
  #pragma unroll
  for (int i = 0; i < 8; ++i) {
    z[2 * i]     = bf2f((u16)(pw[i] & 0xffffu));
    z[2 * i + 1] = bf2f((u16)(pw[i] >> 16));
  }
  #pragma unroll
  for (int r = 0; r < 10; ++r) {
    const float* wr = (r < 5) ? (sbj_w + r * (2 * HID)) : (obj_w + (r - 5) * (2 * HID));
    float p = 0.f;
    #pragma unroll
    for (int m4 = 0; m4 < 4; ++m4) {
      float4 w4 = *(const float4*)(wr + lane * 16 + m4 * 4);
      p += w4.x * z[m4*4] + w4.y * z[m4*4+1] + w4.z * z[m4*4+2] + w4.w * z[m4*4+3];
    }
    #pragma unroll
    for (int offs = 32; offs; offs >>= 1) p += __shfl_down(p, offs);
    if (lane == 0) {
      if (r < 5) em_s[(size_t)wid * NTAG + r]       = p + sbj_b[r];
      else       em_o[(size_t)wid * NTAG + (r - 5)] = p + obj_b[r - 5];
    }
  }
}

// ---------------- CRF NLL per (crf, batch): one wave each ----------------
__global__ void k_crf(const float* __restrict__ em_s, const float* __restrict__ em_o,
                      const int* __restrict__ sbjs, const int* __restrict__ objs,
                      const int* __restrict__ text,
                      const float* __restrict__ s_st, const float* __restrict__ s_en,
                      const float* __restrict__ s_tr,
                      const float* __restrict__ o_st, const float* __restrict__ o_en,
                      const float* __restrict__ o_tr,
                      float* __restrict__ perb, float* __restrict__ cntb)
{
  const int c = blockIdx.x & 1;
  const int b = blockIdx.x >> 1;
  const int j = threadIdx.x;

  const float* em    = c ? em_o : em_s;
  const int*   tags  = c ? objs : sbjs;
  const float* start = c ? o_st : s_st;
  const float* endv  = c ? o_en : s_en;
  const float* trans = c ? o_tr : s_tr;

  float num = 0.f, cnt = 0.f;
  for (int s = j; s < S_LEN; s += 64) {
    const int m = (text[b * S_LEN + s] != 0) ? 1 : 0;
    cnt += (float)m;
    const int tg = tags[b * S_LEN + s];
    if (s == 0) {
      num += start[tg] + em[(size_t)b * NTAG + tg];
    } else if (m) {
      const int tp = tags[b * S_LEN + s - 1];
      num += trans[tp * NTAG + tg] + em[((size_t)s * BATCH + b) * NTAG + tg];
    }
  }
  #pragma unroll
  for (int off = 32; off; off >>= 1) { num += __shfl_down(num, off); cnt += __shfl_down(cnt, off); }
  num = __shfl(num, 0); cnt = __shfl(cnt, 0);
  const int seq_end = (int)cnt - 1;
  if (j == 0) num += endv[tags[b * S_LEN + seq_end]];

  float tr0 = 0, tr1 = 0, tr2 = 0, tr3 = 0, tr4 = 0, st = 0, en = 0;
  if (j < NTAG) {
    tr0 = trans[0 * NTAG + j]; tr1 = trans[1 * NTAG + j]; tr2 = trans[2 * NTAG + j];
    tr3 = trans[3 * NTAG + j]; tr4 = trans[4 * NTAG + j];
    st = start[j]; en = endv[j];
  }
  float alpha = (j < NTAG) ? (st + em[(size_t)b * NTAG + j]) : -1e30f;
  for (int s = 1; s < S_LEN; ++s) {
    const float a0 = __shfl(alpha, 0), a1 = __shfl(alpha, 1), a2 = __shfl(alpha, 2),
                a3 = __shfl(alpha, 3), a4 = __shfl(alpha, 4);
    const int m = (text[b * S_LEN + s] != 0);
    if (j < NTAG) {
      const float v0 = a0 + tr0, v1 = a1 + tr1, v2 = a2 + tr2, v3 = a3 + tr3, v4 = a4 + tr4;
      float mx = fmaxf(fmaxf(fmaxf(v0, v1), fmaxf(v2, v3)), v4);
      float sm = expf(v0 - mx) + expf(v1 - mx) + expf(v2 - mx) + expf(v3 - mx) + expf(v4 - mx);
      float nxt = mx + logf(sm) + em[((size_t)s * BATCH + b) * NTAG + j];
      if (m) alpha = nxt;
    }
  }
  float v  = (j < NTAG) ? (alpha + en) : -1e30f;
  float mx = v;
  #pragma unroll
  for (int off = 1; off < 8; off <<= 1) mx = fmaxf(mx, __shfl_xor(mx, off));
  float ex = (j < NTAG) ? expf(v - mx) : 0.f;
  #pragma unroll
  for (int off = 1; off < 8; off <<= 1) ex += __shfl_xor(ex, off);
  if (j == 0) {
    perb[c * BATCH + b] = num - (mx + logf(ex));
    cntb[c * BATCH + b] = cnt;
  }
}

__global__ void k_final(const float* __restrict__ perb, const float* __restrict__ cntb,
                        float* __restrict__ out)
{
  if (threadIdx.x == 0 && blockIdx.x == 0) {
    float s0 = 0, c0 = 0, s1 = 0, c1 = 0;
    for (int b = 0; b < BATCH; ++b) {
      s0 += perb[b];         c0 += cntb[b];
      s1 += perb[BATCH + b]; c1 += cntb[BATCH + b];
    }
    const float ls = -s0 / c0, lo = -s1 / c1;
    out[0] = 2.f * (ls + lo);
    out[1] = ls;
    out[2] = lo;
  }
}

extern "C" void kernel_launch(void* const* d_in, const int* in_sizes, int n_in,
                              void* d_out, int out_size, void* d_ws, size_t ws_size,
                              hipStream_t stream)
{
  const int*   text  = (const int*)d_in[0];
  const int*   sbjs  = (const int*)d_in[1];
  const int*   objs  = (const int*)d_in[2];
  const float* emb   = (const float*)d_in[3];
  const float* wih_f = (const float*)d_in[4];
  const float* whh_f = (const float*)d_in[5];
  const float* bih_f = (const float*)d_in[6];
  const float* bhh_f = (const float*)d_in[7];
  const float* wih_b = (const float*)d_in[8];
  const float* whh_b = (const float*)d_in[9];
  const float* bih_b = (const float*)d_in[10];
  const float* bhh_b = (const float*)d_in[11];
  const float* sbj_w = (const float*)d_in[12];
  const float* sbj_b = (const float*)d_in[13];
  const float* obj_w = (const float*)d_in[14];
  const float* obj_b = (const float*)d_in[15];
  const float* s_st  = (const float*)d_in[16];
  const float* s_en  = (const float*)d_in[17];
  const float* s_tr  = (const float*)d_in[18];
  const float* o_st  = (const float*)d_in[19];
  const float* o_en  = (const float*)d_in[20];
  const float* o_tr  = (const float*)d_in[21];

  char* w = (char*)d_ws;
  u16*   Wcat  = (u16*)(w + 0);            //  6,291,456 B
  float* bias  = (float*)(w + 6291456);    //     16,384 B
  u16*   xz    = (u16*)(w + 6307840);      // 16,777,216 B
  u16*   hbuf  = (u16*)(w + 23085056);     // 67,108,864 B
  float* em_s  = (float*)(w + 90193920);   //    655,360 B
  float* em_o  = (float*)(w + 90849280);   //    655,360 B
  float* perb  = (float*)(w + 91504640);   //        512 B
  float* cntb  = (float*)(w + 91505152);   //        512 B
  int*   flags = (int*)(w + 91505664);     //        256 B

  hipMemsetAsync(flags, 0, 2 * 32 * sizeof(int), stream);

  k_prep_w<<<3072, 256, 0, stream>>>(wih_f, whh_f, bih_f, bhh_f,
                                     wih_b, whh_b, bih_b, bhh_b, Wcat, bias);
  k_embed<<<8192, 256, 0, stream>>>(text, emb, xz);

  void* args[] = { (void*)&Wcat, (void*)&bias, (void*)&xz, (void*)&hbuf, (void*)&flags };
  hipLaunchCooperativeKernel((const void*)k_lstm, dim3(64), dim3(256), args, 0, stream);

  k_heads<<<8192, 256, 0, stream>>>(hbuf, sbj_w, sbj_b, obj_w, obj_b, em_s, em_o);
  k_crf<<<128, 64, 0, stream>>>(em_s, em_o, sbjs, objs, text,
                                s_st, s_en, s_tr, o_st, o_en, o_tr, perb, cntb);
  k_final<<<1, 1, 0, stream>>>(perb, cntb, (float*)d_out);
}

// Round 11
// 4204.015 us; speedup vs baseline: 1.4628x; 1.4325x over previous
//
#include <hip/hip_runtime.h>
#include <hip/hip_bf16.h>

#define S_LEN 512
#define BATCH 64
#define EMB_D 256
#define HID   512
#define NTAG  5

typedef unsigned short u16;
typedef unsigned long long u64;
typedef __attribute__((ext_vector_type(8)))  short bf16x8;
typedef __attribute__((ext_vector_type(16))) float f32x16;

__device__ __forceinline__ float bf2f(u16 u) {
  union { unsigned int i; float f; } v; v.i = ((unsigned int)u) << 16; return v.f;
}
__device__ __forceinline__ u16 f2bf(float f) {
  __hip_bfloat16 h = __float2bfloat16(f);
  union { __hip_bfloat16 h; u16 u; } v; v.h = h; return v.u;
}
__device__ __forceinline__ float sigm(float x) { return 1.0f / (1.0f + __expf(-x)); }
__device__ __forceinline__ float ftanh(float x) {
  float ax = fabsf(x);
  float e  = __expf(-2.0f * ax);
  float t  = (1.0f - e) / (1.0f + e);
  return copysignf(t, x);
}

// pinned 16B global load, normal caching (read-only weights, loaded once;
// asm prevents rematerialization under register pressure)
__device__ __forceinline__ bf16x8 ldg_pin16(const u16* p) {
  float4 r;
  asm volatile("global_load_dwordx4 %0, %1, off" : "=v"(r) : "v"(p));
  return __builtin_bit_cast(bf16x8, r);
}

// ---------------- weight prep: Wcat bf16 [2][2048][768] = [Wih | Whh], bias fp32 [2][2048]
__global__ void k_prep_w(const float* __restrict__ wihf, const float* __restrict__ whhf,
                         const float* __restrict__ bihf, const float* __restrict__ bhhf,
                         const float* __restrict__ wihb, const float* __restrict__ whhb,
                         const float* __restrict__ bihb, const float* __restrict__ bhhb,
                         u16* __restrict__ Wcat, float* __restrict__ bias)
{
  const int gid = blockIdx.x * blockDim.x + threadIdx.x;
  const int k4  = gid % 192;
  const int rem = gid / 192;
  const int row = rem & 2047;
  const int d   = rem >> 11;
  const float* wih = d ? wihb : wihf;
  const float* whh = d ? whhb : whhf;
  const int k = k4 * 4;
  float4 v;
  if (k < EMB_D) v = *(const float4*)(wih + (size_t)row * EMB_D + k);
  else           v = *(const float4*)(whh + (size_t)row * HID + (k - EMB_D));
  union { u16 u[4]; uint2 q; } pk;
  pk.u[0] = f2bf(v.x); pk.u[1] = f2bf(v.y); pk.u[2] = f2bf(v.z); pk.u[3] = f2bf(v.w);
  *(uint2*)(Wcat + ((size_t)(d * 2048 + row)) * 768 + k) = pk.q;
  if (gid < 4096) {
    const int dd = gid >> 11, r = gid & 2047;
    bias[gid] = dd ? (bihb[r] + bhhb[r]) : (bihf[r] + bhhf[r]);
  }
}

// ---------------- embedding gather -> xz bf16 [S][B][EMB]
__global__ void k_embed(const int* __restrict__ text, const float* __restrict__ emb,
                        u16* __restrict__ xz)
{
  const int gid = blockIdx.x * blockDim.x + threadIdx.x;
  const int e4 = gid & 63;
  const int sb = gid >> 6;
  const int b  = sb & 63;
  const int s  = sb >> 6;
  const int row = text[b * S_LEN + s];
  float4 v = *(const float4*)(emb + (size_t)row * EMB_D + e4 * 4);
  union { u16 u[4]; uint2 q; } pk;
  pk.u[0] = f2bf(v.x); pk.u[1] = f2bf(v.y); pk.u[2] = f2bf(v.z); pk.u[3] = f2bf(v.w);
  *(uint2*)(xz + ((size_t)(s * BATCH + b)) * EMB_D + e4 * 4) = pk.q;
}

// ---------------- persistent MFMA BiLSTM ----------------
// 64 blocks x 4 waves. Block: d = bid>>5, wb = bid&31, hid base k0 = wb*16.
// Wave: rt = w>>1 (8 hidden units), nt = w&1 (batch half).
// hbuf layout: [d][t][wb][batch=64][hid16=16] bf16 -> each block's per-step h
// slice is ONE contiguous 2KB region (coalesced full-line write-through stores,
// single writer per MALL line). Reader fragment c == writer-c's region:
// u16 offset c*1024 + bcol*16 + lhi*8 (16B contiguous).
// Flags: 256B (one MALL line) per writer -> no line-level store serialization.
__launch_bounds__(256, 1)
__global__ void k_lstm(const u16* __restrict__ Wcat, const float* __restrict__ bias,
                       const u16* __restrict__ xz, u16* __restrict__ hbuf,
                       int* __restrict__ flags)
{
  __shared__ u64 hlds[256];   // [batch64][hid16] as u64 quads: idx = batch*4 + hid16/4

  const int bid  = blockIdx.x;
  const int d    = bid >> 5;
  const int wb   = bid & 31;
  const int k0   = wb * 16;
  const int tid  = threadIdx.x;
  const int w    = tid >> 6;
  const int lane = tid & 63;
  const int rt   = w >> 1, nt = w & 1;
  const int ln31 = lane & 31, lhi = lane >> 5;
  const int hbase = k0 + rt * 8;
  const int bcol  = nt * 32 + ln31;

  // ---- A fragments, pinned in registers (read-only data, loaded once) ----
  bf16x8 af[48];
  {
    const int m    = ln31;
    const int grow = (m >> 3) * HID + hbase + (m & 7);
    const u16* wr  = Wcat + ((size_t)(d * 2048 + grow)) * 768 + lhi * 8;
    #pragma unroll
    for (int ks = 0; ks < 48; ++ks) af[ks] = ldg_pin16(wr + ks * 16);
  }
  asm volatile("s_waitcnt vmcnt(0)" ::: "memory");
  __builtin_amdgcn_sched_barrier(0);

  // ---- per-lane bias seed (gate q, hid_local i+4*lhi) ----
  float bsv[16];
  #pragma unroll
  for (int q = 0; q < 4; ++q)
    #pragma unroll
    for (int i = 0; i < 4; ++i)
      bsv[q * 4 + i] = bias[d * 2048 + q * HID + hbase + 4 * lhi + i];
  float cst[4] = {0.f, 0.f, 0.f, 0.f};

  const int* myflag = flags + (d * 32 + ln31) * 64;   // one line per writer

  for (int it = 0; it < S_LEN; ++it) {
    const int t = d ? (S_LEN - 1 - it) : it;

    // two accumulators halve the dependent-MFMA chain; combined at the cell
    f32x16 acc0, acc1;
    #pragma unroll
    for (int r = 0; r < 16; ++r) { acc0[r] = bsv[r]; acc1[r] = 0.f; }

    // ---- x-part (independent of h; L2-hot; overlaps the poll below) ----
    {
      const u16* xb = xz + ((size_t)t * BATCH + bcol) * EMB_D + lhi * 8;
      #pragma unroll
      for (int c = 0; c < 16; ++c) {
        bf16x8 xf = *(const bf16x8*)(xb + c * 16);
        if (c & 1) acc1 = __builtin_amdgcn_mfma_f32_32x32x16_bf16(af[c], xf, acc1, 0, 0, 0);
        else       acc0 = __builtin_amdgcn_mfma_f32_32x32x16_bf16(af[c], xf, acc0, 0, 0, 0);
      }
    }

    // ---- wait for h_{prev}: lanes 0..31 poll 32 independent flag lines ----
    if (it > 0) {
      for (;;) {
        const int v = __hip_atomic_load(myflag, __ATOMIC_RELAXED,
                                        __HIP_MEMORY_SCOPE_AGENT);
        if (__all(v >= it)) break;
        __builtin_amdgcn_s_sleep(1);
      }
      __builtin_amdgcn_fence(__ATOMIC_ACQUIRE, "workgroup");  // order poll -> loads

      const int tprev = d ? (t + 1) : (t - 1);
      // fragment c lives in writer-c's region: u64 idx = c*256 + bcol*4 + lhi*2
      const u64* hb = (const u64*)(hbuf + ((size_t)d * S_LEN + tprev) * 32768);
      #pragma unroll
      for (int c = 0; c < 32; ++c) {
        union { u64 q[2]; bf16x8 v; } hf;
        hf.q[0] = __hip_atomic_load(hb + c * 256 + bcol * 4 + lhi * 2,
                                    __ATOMIC_RELAXED, __HIP_MEMORY_SCOPE_AGENT);
        hf.q[1] = __hip_atomic_load(hb + c * 256 + bcol * 4 + lhi * 2 + 1,
                                    __ATOMIC_RELAXED, __HIP_MEMORY_SCOPE_AGENT);
        if (c & 1) acc1 = __builtin_amdgcn_mfma_f32_32x32x16_bf16(af[16 + c], hf.v, acc1, 0, 0, 0);
        else       acc0 = __builtin_amdgcn_mfma_f32_32x32x16_bf16(af[16 + c], hf.v, acc0, 0, 0, 0);
      }
    }

    // ---- LSTM cell, fully per-lane ----
    u16 hu[4];
    #pragma unroll
    for (int i = 0; i < 4; ++i) {
      const float gi = acc0[i]      + acc1[i];
      const float gf = acc0[4 + i]  + acc1[4 + i];
      const float gg = acc0[8 + i]  + acc1[8 + i];
      const float go = acc0[12 + i] + acc1[12 + i];
      const float ig = sigm(gi), fg = sigm(gf), g2 = ftanh(gg), og = sigm(go);
      cst[i] = fg * cst[i] + ig * g2;
      hu[i] = f2bf(og * ftanh(cst[i]));
    }
    const u64 pk = (u64)hu[0] | ((u64)hu[1] << 16) | ((u64)hu[2] << 32) | ((u64)hu[3] << 48);

    // ---- LDS remap -> coalesced contiguous 2KB block store ----
    hlds[bcol * 4 + rt * 2 + lhi] = pk;   // [batch][hid16-quad]
    __syncthreads();
    {
      u64* hw = (u64*)(hbuf + (((size_t)d * S_LEN + t) * 32 + wb) * 1024);
      __hip_atomic_store(hw + tid, hlds[tid],
                         __ATOMIC_RELAXED, __HIP_MEMORY_SCOPE_AGENT);  // 8B/thread, coalesced
    }
    __syncthreads();   // vmcnt(0) drain: all 2KB acked at MALL; also protects hlds reuse
    if (tid == 0)
      __hip_atomic_store(flags + (d * 32 + wb) * 64, it + 1,
                         __ATOMIC_RELAXED, __HIP_MEMORY_SCOPE_AGENT);
  }
}

// ---------------- heads: em[s][b][j] = [hf;hb] . w[j] + bias[j] ----------------
__global__ void k_heads(const u16* __restrict__ hbuf,
                        const float* __restrict__ sbj_w, const float* __restrict__ sbj_b,
                        const float* __restrict__ obj_w, const float* __restrict__ obj_b,
                        float* __restrict__ em_s, float* __restrict__ em_o)
{
  const int wid  = blockIdx.x * 4 + (threadIdx.x >> 6);
  const int lane = threadIdx.x & 63;
  if (wid >= S_LEN * BATCH) return;
  const int s = wid >> 6, b = wid & 63;
  const int dsel = lane >> 5;
  const int off  = (lane * 16) & 511;         // hid chunk [off, off+16)
  // layout [d][t][wb][batch][16]: chunk off -> region wb=off>>4, 32B contiguous
  const u16* src = hbuf + ((size_t)dsel * S_LEN + s) * 32768
                        + (off >> 4) * 1024 + b * 16;
  uint4 p0 = *(const uint4*)(src);
  uint4 p1 = *(const uint4*)(src + 8);
  unsigned int pw[8] = { p0.x, p0.y, p0.z, p0.w, p1.x, p1.y, p1.z, p1.w };
  float z[16];
  #pragma unroll
  for (int i = 0; i < 8; ++i) {
    z[2 * i]     = bf2f((u16)(pw[i] & 0xffffu));
    z[2 * i + 1] = bf2f((u16)(pw[i] >> 16));
  }
  #pragma unroll
  for (int r = 0; r < 10; ++r) {
    const float* wr = (r < 5) ? (sbj_w + r * (2 * HID)) : (obj_w + (r - 5) * (2 * HID));
    float p = 0.f;
    #pragma unroll
    for (int m4 = 0; m4 < 4; ++m4) {
      float4 w4 = *(const float4*)(wr + lane * 16 + m4 * 4);
      p += w4.x * z[m4*4] + w4.y * z[m4*4+1] + w4.z * z[m4*4+2] + w4.w * z[m4*4+3];
    }
    #pragma unroll
    for (int offs = 32; offs; offs >>= 1) p += __shfl_down(p, offs);
    if (lane == 0) {
      if (r < 5) em_s[(size_t)wid * NTAG + r]       = p + sbj_b[r];
      else       em_o[(size_t)wid * NTAG + (r - 5)] = p + obj_b[r - 5];
    }
  }
}

// ---------------- CRF NLL per (crf, batch): one wave each ----------------
__global__ void k_crf(const float* __restrict__ em_s, const float* __restrict__ em_o,
                      const int* __restrict__ sbjs, const int* __restrict__ objs,
                      const int* __restrict__ text,
                      const float* __restrict__ s_st, const float* __restrict__ s_en,
                      const float* __restrict__ s_tr,
                      const float* __restrict__ o_st, const float* __restrict__ o_en,
                      const float* __restrict__ o_tr,
                      float* __restrict__ perb, float* __restrict__ cntb)
{
  const int c = blockIdx.x & 1;
  const int b = blockIdx.x >> 1;
  const int j = threadIdx.x;

  const float* em    = c ? em_o : em_s;
  const int*   tags  = c ? objs : sbjs;
  const float* start = c ? o_st : s_st;
  const float* endv  = c ? o_en : s_en;
  const float* trans = c ? o_tr : s_tr;

  float num = 0.f, cnt = 0.f;
  for (int s = j; s < S_LEN; s += 64) {
    const int m = (text[b * S_LEN + s] != 0) ? 1 : 0;
    cnt += (float)m;
    const int tg = tags[b * S_LEN + s];
    if (s == 0) {
      num += start[tg] + em[(size_t)b * NTAG + tg];
    } else if (m) {
      const int tp = tags[b * S_LEN + s - 1];
      num += trans[tp * NTAG + tg] + em[((size_t)s * BATCH + b) * NTAG + tg];
    }
  }
  #pragma unroll
  for (int off = 32; off; off >>= 1) { num += __shfl_down(num, off); cnt += __shfl_down(cnt, off); }
  num = __shfl(num, 0); cnt = __shfl(cnt, 0);
  const int seq_end = (int)cnt - 1;
  if (j == 0) num += endv[tags[b * S_LEN + seq_end]];

  float tr0 = 0, tr1 = 0, tr2 = 0, tr3 = 0, tr4 = 0, st = 0, en = 0;
  if (j < NTAG) {
    tr0 = trans[0 * NTAG + j]; tr1 = trans[1 * NTAG + j]; tr2 = trans[2 * NTAG + j];
    tr3 = trans[3 * NTAG + j]; tr4 = trans[4 * NTAG + j];
    st = start[j]; en = endv[j];
  }
  float alpha = (j < NTAG) ? (st + em[(size_t)b * NTAG + j]) : -1e30f;
  for (int s = 1; s < S_LEN; ++s) {
    const float a0 = __shfl(alpha, 0), a1 = __shfl(alpha, 1), a2 = __shfl(alpha, 2),
                a3 = __shfl(alpha, 3), a4 = __shfl(alpha, 4);
    const int m = (text[b * S_LEN + s] != 0);
    if (j < NTAG) {
      const float v0 = a0 + tr0, v1 = a1 + tr1, v2 = a2 + tr2, v3 = a3 + tr3, v4 = a4 + tr4;
      float mx = fmaxf(fmaxf(fmaxf(v0, v1), fmaxf(v2, v3)), v4);
      float sm = expf(v0 - mx) + expf(v1 - mx) + expf(v2 - mx) + expf(v3 - mx) + expf(v4 - mx);
      float nxt = mx + logf(sm) + em[((size_t)s * BATCH + b) * NTAG + j];
      if (m) alpha = nxt;
    }
  }
  float v  = (j < NTAG) ? (alpha + en) : -1e30f;
  float mx = v;
  #pragma unroll
  for (int off = 1; off < 8; off <<= 1) mx = fmaxf(mx, __shfl_xor(mx, off));
  float ex = (j < NTAG) ? expf(v - mx) : 0.f;
  #pragma unroll
  for (int off = 1; off < 8; off <<= 1) ex += __shfl_xor(ex, off);
  if (j == 0) {
    perb[c * BATCH + b] = num - (mx + logf(ex));
    cntb[c * BATCH + b] = cnt;
  }
}

__global__ void k_final(const float* __restrict__ perb, const float* __restrict__ cntb,
                        float* __restrict__ out)
{
  if (threadIdx.x == 0 && blockIdx.x == 0) {
    float s0 = 0, c0 = 0, s1 = 0, c1 = 0;
    for (int b = 0; b < BATCH; ++b) {
      s0 += perb[b];         c0 += cntb[b];
      s1 += perb[BATCH + b]; c1 += cntb[BATCH + b];
    }
    const float ls = -s0 / c0, lo = -s1 / c1;
    out[0] = 2.f * (ls + lo);
    out[1] = ls;
    out[2] = lo;
  }
}

extern "C" void kernel_launch(void* const* d_in, const int* in_sizes, int n_in,
                              void* d_out, int out_size, void* d_ws, size_t ws_size,
                              hipStream_t stream)
{
  const int*   text  = (const int*)d_in[0];
  const int*   sbjs  = (const int*)d_in[1];
  const int*   objs  = (const int*)d_in[2];
  const float* emb   = (const float*)d_in[3];
  const float* wih_f = (const float*)d_in[4];
  const float* whh_f = (const float*)d_in[5];
  const float* bih_f = (const float*)d_in[6];
  const float* bhh_f = (const float*)d_in[7];
  const float* wih_b = (const float*)d_in[8];
  const float* whh_b = (const float*)d_in[9];
  const float* bih_b = (const float*)d_in[10];
  const float* bhh_b = (const float*)d_in[11];
  const float* sbj_w = (const float*)d_in[12];
  const float* sbj_b = (const float*)d_in[13];
  const float* obj_w = (const float*)d_in[14];
  const float* obj_b = (const float*)d_in[15];
  const float* s_st  = (const float*)d_in[16];
  const float* s_en  = (const float*)d_in[17];
  const float* s_tr  = (const float*)d_in[18];
  const float* o_st  = (const float*)d_in[19];
  const float* o_en  = (const float*)d_in[20];
  const float* o_tr  = (const float*)d_in[21];

  char* w = (char*)d_ws;
  u16*   Wcat  = (u16*)(w + 0);            //  6,291,456 B
  float* bias  = (float*)(w + 6291456);    //     16,384 B
  u16*   xz    = (u16*)(w + 6307840);      // 16,777,216 B
  u16*   hbuf  = (u16*)(w + 23085056);     // 67,108,864 B
  float* em_s  = (float*)(w + 90193920);   //    655,360 B
  float* em_o  = (float*)(w + 90849280);   //    655,360 B
  float* perb  = (float*)(w + 91504640);   //        512 B
  float* cntb  = (float*)(w + 91505152);   //        512 B
  int*   flags = (int*)(w + 91505664);     //     16,384 B (64 writers x 256B)

  hipMemsetAsync(flags, 0, 2 * 32 * 64 * sizeof(int), stream);

  k_prep_w<<<3072, 256, 0, stream>>>(wih_f, whh_f, bih_f, bhh_f,
                                     wih_b, whh_b, bih_b, bhh_b, Wcat, bias);
  k_embed<<<8192, 256, 0, stream>>>(text, emb, xz);

  void* args[] = { (void*)&Wcat, (void*)&bias, (void*)&xz, (void*)&hbuf, (void*)&flags };
  hipLaunchCooperativeKernel((const void*)k_lstm, dim3(64), dim3(256), args, 0, stream);

  k_heads<<<8192, 256, 0, stream>>>(hbuf, sbj_w, sbj_b, obj_w, obj_b, em_s, em_o);
  k_crf<<<128, 64, 0, stream>>>(em_s, em_o, sbjs, objs, text,
                                s_st, s_en, s_tr, o_st, o_en, o_tr, perb, cntb);
  k_final<<<1, 1, 0, stream>>>(perb, cntb, (float*)d_out);
}